// Round 10
// baseline (313.643 us; speedup 1.0000x reference)
//
#include <hip/hip_runtime.h>

#define N_NODES 50000
#define IN_CH   128
#define HID_CH  256
#define OUT_CH  128

#define NB    196          // buckets: dst>>8
#define NWG   64           // phase-1 workgroups
#define NBNW  (NB * NWG)   // 12544 = 256 * 49
#define SCHUNK 49          // scan elements per thread (12544/256)

#define XBLK  3125         // cvt-x blocks: 50000*128/8/256
#define WBLK  64           // cvt-weights blocks: 4*4096/256

typedef __attribute__((ext_vector_type(8))) short bf16x8;
typedef __attribute__((ext_vector_type(4))) float f32x4;

__device__ __forceinline__ unsigned short f32_bf16_rne(float f) {
    unsigned u = __float_as_uint(f);
    unsigned r = u + 0x7fff + ((u >> 16) & 1);
    return (unsigned short)(r >> 16);
}
__device__ __forceinline__ float bf16lo_f32(unsigned u) { return __uint_as_float(u << 16); }
__device__ __forceinline__ float bf16hi_f32(unsigned u) { return __uint_as_float(u & 0xffff0000u); }

__device__ __forceinline__ void cvt8(const float* __restrict__ in,
                                     unsigned short* __restrict__ outp, size_t j)
{
    const float4* p = reinterpret_cast<const float4*>(in) + 2 * j;
    float4 a = p[0], b = p[1];
    alignas(16) unsigned short t[8] = {
        f32_bf16_rne(a.x), f32_bf16_rne(a.y), f32_bf16_rne(a.z), f32_bf16_rne(a.w),
        f32_bf16_rne(b.x), f32_bf16_rne(b.y), f32_bf16_rne(b.z), f32_bf16_rne(b.w)};
    *reinterpret_cast<int4*>(outp + 8 * j) = *reinterpret_cast<const int4*>(t);
}

// ---------------------------------------------------------------------------
// prep: role-dispatched fusion of {bucket-count, cvt x, cvt weights}
// ---------------------------------------------------------------------------
__global__ __launch_bounds__(256) void prep_kernel(
    const int* __restrict__ src, const int* __restrict__ dst,
    int* __restrict__ counts, int E, int chunk,
    const float* __restrict__ x, unsigned short* __restrict__ xb,
    const float* __restrict__ W1l, const float* __restrict__ W1r,
    const float* __restrict__ W2l, const float* __restrict__ W2r,
    unsigned short* __restrict__ W1lb, unsigned short* __restrict__ W1rb,
    unsigned short* __restrict__ W2lb, unsigned short* __restrict__ W2rb)
{
    const int b = blockIdx.x;
    if (b < NWG) {
        __shared__ int h[NB];
        for (int i = threadIdx.x; i < NB; i += 256) h[i] = 0;
        __syncthreads();
        const int e0 = b * chunk;
        const int e1 = min(e0 + chunk, E);
        for (int e = e0 + threadIdx.x; e < e1; e += 256) {
            int s = src[e], d = dst[e];
            if ((unsigned)s < (unsigned)N_NODES && (unsigned)d < (unsigned)N_NODES)
                atomicAdd(&h[d >> 8], 1);
        }
        __syncthreads();
        for (int i = threadIdx.x; i < NB; i += 256)
            counts[i * NWG + b] = h[i];
    } else if (b < NWG + XBLK) {
        size_t j = (size_t)(b - NWG) * 256 + threadIdx.x;   // < 800000 exactly
        cvt8(x, xb, j);
    } else {
        int idx = (b - NWG - XBLK) * 256 + threadIdx.x;     // 0..16383
        int seg = idx >> 12, j = idx & 4095;
        const float* in = (seg == 0) ? W1l : (seg == 1) ? W1r : (seg == 2) ? W2l : W2r;
        unsigned short* o = (seg == 0) ? W1lb : (seg == 1) ? W1rb : (seg == 2) ? W2lb : W2rb;
        cvt8(in, o, (size_t)j);
    }
}

// ---------------------------------------------------------------------------
// Single-block exclusive scan of counts[NBNW] -> S, S[NBNW] = total
// ---------------------------------------------------------------------------
__global__ __launch_bounds__(256) void scan_all_kernel(
    const int* __restrict__ counts, int* __restrict__ S)
{
    __shared__ int tot[256];
    const int t = threadIdx.x;
    const int base = t * SCHUNK;
    int loc[SCHUNK];
    int sum = 0;
#pragma unroll
    for (int k = 0; k < SCHUNK; ++k) {
        loc[k] = sum;
        sum += counts[base + k];
    }
    tot[t] = sum;
    __syncthreads();
    for (int off = 1; off < 256; off <<= 1) {
        int v = (t >= off) ? tot[t - off] : 0;
        __syncthreads();
        if (t >= off) tot[t] += v;
        __syncthreads();
    }
    int offv = (t == 0) ? 0 : tot[t - 1];
#pragma unroll
    for (int k = 0; k < SCHUNK; ++k)
        S[base + k] = loc[k] + offv;
    if (t == 255) S[NBNW] = offv + sum;
}

// ---------------------------------------------------------------------------
// Scatter packed (src<<8 | dst&255) into (bucket,wg)-exclusive subregions.
// ---------------------------------------------------------------------------
__global__ __launch_bounds__(256) void bscatter_kernel(
    const int* __restrict__ src, const int* __restrict__ dst,
    const int* __restrict__ S, int* __restrict__ pairs, int E, int chunk)
{
    __shared__ int cur[NB];
    const int w = blockIdx.x;
    for (int i = threadIdx.x; i < NB; i += 256) cur[i] = S[i * NWG + w];
    __syncthreads();
    const int e0 = w * chunk;
    const int e1 = min(e0 + chunk, E);
    for (int e = e0 + threadIdx.x; e < e1; e += 256) {
        int s = src[e], d = dst[e];
        if ((unsigned)s < (unsigned)N_NODES && (unsigned)d < (unsigned)N_NODES) {
            int pos = atomicAdd(&cur[d >> 8], 1);
            pairs[pos] = (s << 8) | (d & 255);
        }
    }
}

// ---------------------------------------------------------------------------
// Per-bucket local counting sort -> rowptr + colidx
// ---------------------------------------------------------------------------
__global__ __launch_bounds__(256) void bsort_kernel(
    const int* __restrict__ pairs, const int* __restrict__ S,
    int* __restrict__ rowptr, int* __restrict__ colidx)
{
    __shared__ int hcnt[256];
    __shared__ int hcur[256];
    const int b = blockIdx.x;
    const int start = S[b * NWG];
    const int endv  = (b == NB - 1) ? S[NBNW] : S[(b + 1) * NWG];

    hcnt[threadIdx.x] = 0;
    __syncthreads();
    for (int e = start + threadIdx.x; e < endv; e += 256)
        atomicAdd(&hcnt[pairs[e] & 255], 1);
    __syncthreads();
    for (int off = 1; off < 256; off <<= 1) {
        int t = (threadIdx.x >= off) ? hcnt[threadIdx.x - off] : 0;
        __syncthreads();
        if (threadIdx.x >= off) hcnt[threadIdx.x] += t;
        __syncthreads();
    }
    int offv = (threadIdx.x == 0) ? 0 : hcnt[threadIdx.x - 1];
    hcur[threadIdx.x] = offv;
    int node = (b << 8) + threadIdx.x;
    if (node < N_NODES) rowptr[node] = start + offv;
    if (b == NB - 1 && threadIdx.x == 0) rowptr[N_NODES] = endv;
    __syncthreads();
    for (int e = start + threadIdx.x; e < endv; e += 256) {
        int p = pairs[e];
        int pos = atomicAdd(&hcur[p & 255], 1);
        colidx[start + pos] = (unsigned)p >> 8;
    }
}

// ---------------------------------------------------------------------------
// Channel-sliced aggregates with DIAGONAL slice swizzle.
// r9 lesson: slice = blockIdx.y gave every gather the same 64 B offset within
// the 256 B row -> line stride of 4 -> only 1/4 of L2 sets usable -> 1 MB
// effective capacity -> thrash (FETCH 124 MB, 71 us). Fix: slice for a node
// is (blockIdx.y + node) & 3, so each pass touches all 4 intra-row offsets
// uniformly (all sets usable; working set 3.2 MB < 4 MB per-XCD L2), and the
// 4 passes still cover each channel exactly once.
// ---------------------------------------------------------------------------
#define ACC4(v)                                                 \
    acc[0] += bf16lo_f32(v.x); acc[1] += bf16hi_f32(v.x);       \
    acc[2] += bf16lo_f32(v.y); acc[3] += bf16hi_f32(v.y);

#define AGG_BODY(CH)                                                            \
    const int node = blockIdx.x * 4 + (threadIdx.x >> 6);                       \
    if (node >= N_NODES) return;                                                \
    const int lane = threadIdx.x & 63;                                          \
    const int grp = lane >> 3;                 /* 0..7 */                       \
    const int sl = (blockIdx.y + node) & 3;    /* diagonal slice swizzle */     \
    const int chOff = sl * 32 + (lane & 7) * 4;                                 \
    const int beg = rowptr[node], end = rowptr[node + 1];                       \
    const int len = end - beg;                                                  \
    const int q = (len + 7) >> 3;                                               \
    int j  = beg + grp * q;                                                     \
    int j1 = min(j + q, end);                                                   \
    float acc[4] = {};                                                          \
    for (; j + 1 < j1; j += 2) {                                                \
        int s0 = colidx[j], s1 = colidx[j + 1];                                 \
        int2 v0 = *reinterpret_cast<const int2*>(feat + (size_t)s0 * CH + chOff); \
        int2 v1 = *reinterpret_cast<const int2*>(feat + (size_t)s1 * CH + chOff); \
        ACC4(v0) ACC4(v1)                                                       \
    }                                                                           \
    if (j < j1) {                                                               \
        int s0 = colidx[j];                                                     \
        int2 v0 = *reinterpret_cast<const int2*>(feat + (size_t)s0 * CH + chOff); \
        ACC4(v0)                                                                \
    }                                                                           \
    _Pragma("unroll")                                                           \
    for (int k = 0; k < 4; ++k) {                                               \
        acc[k] += __shfl_xor(acc[k], 8);                                        \
        acc[k] += __shfl_xor(acc[k], 16);                                       \
        acc[k] += __shfl_xor(acc[k], 32);                                       \
    }                                                                           \
    const float sc = 1.0f / fmaxf((float)len, 1.0f);

__global__ __launch_bounds__(256) void agg1_kernel(
    const unsigned short* __restrict__ feat, const int* __restrict__ rowptr,
    const int* __restrict__ colidx, unsigned short* __restrict__ outp)
{
    AGG_BODY(IN_CH)
    if (grp == 0) {
        alignas(8) unsigned short t[4];
#pragma unroll
        for (int k = 0; k < 4; ++k) t[k] = f32_bf16_rne(acc[k] * sc);
        *reinterpret_cast<int2*>(outp + (size_t)node * IN_CH + chOff) =
            *reinterpret_cast<const int2*>(t);
    }
}

__global__ __launch_bounds__(256) void agg2_kernel(
    const unsigned short* __restrict__ feat, const int* __restrict__ rowptr,
    const int* __restrict__ colidx, float* __restrict__ out)
{
    AGG_BODY(OUT_CH)
    if (grp == 0) {
        float* o = out + (size_t)node * OUT_CH + chOff;
        float4 ov = *reinterpret_cast<float4*>(o);
        ov.x += acc[0] * sc; ov.y += acc[1] * sc;
        ov.z += acc[2] * sc; ov.w += acc[3] * sc;
        *reinterpret_cast<float4*>(o) = ov;
    }
}

// ---------------------------------------------------------------------------
// MFMA GEMMs — 128x128 block tile, 4 waves (2x2), wave tile 64x64,
// mfma(b, a, acc) swapped epilogue (D[chan][node], vector stores).
// global->LDS via __builtin_amdgcn_global_load_lds width=16 with XOR chunk
// swizzle (r8; measured ~neutral vs ds_write staging — kept for lower LDS).
// ---------------------------------------------------------------------------
__device__ __forceinline__ void stage_async(
    const unsigned short* __restrict__ g, int ldg, int rowBase, int maxRow,
    int kBase, unsigned short* __restrict__ s, int tid)
{
    const int wave = tid >> 6;          // wave-uniform
    const int lane = tid & 63;
    const int r_in = lane >> 3;         // 0..7 within 8-row group
    const int c_g  = (lane & 7) ^ r_in; // fetch the chunk destined for this lane's LDS slot
#pragma unroll
    for (int it = 0; it < 4; ++it) {
        const int rowBlk = it * 32 + wave * 8;        // wave-uniform
        int row = rowBase + rowBlk + r_in;
        if (row >= maxRow) row = maxRow - 1;          // clamp; epilogue guards stores
        const unsigned short* gp = g + (size_t)row * ldg + kBase + c_g * 8;
        unsigned short* lp = s + rowBlk * 64;         // wave-uniform; HW adds lane*16
        __builtin_amdgcn_global_load_lds(
            (const __attribute__((address_space(1))) unsigned int*)gp,
            (__attribute__((address_space(3))) unsigned int*)lp,
            16, 0, 0);
    }
}

__device__ __forceinline__ const bf16x8* frag_ptr(
    const unsigned short* __restrict__ s, int rr, int c)
{
    return reinterpret_cast<const bf16x8*>(s + rr * 64 + (((c ^ (rr & 7))) << 3));
}

__device__ __forceinline__ void mfma_tile(
    const unsigned short* __restrict__ As, const unsigned short* __restrict__ Bs,
    int wm, int wn, int l16, int quad, f32x4 acc[4][4])
{
#pragma unroll
    for (int k0 = 0; k0 < 64; k0 += 32) {
        const int c = (k0 >> 3) + quad;   // 16 B chunk index within row
        bf16x8 a[4], b[4];
#pragma unroll
        for (int i = 0; i < 4; ++i)
            a[i] = *frag_ptr(As, wm * 64 + i * 16 + l16, c);
#pragma unroll
        for (int j = 0; j < 4; ++j)
            b[j] = *frag_ptr(Bs, wn * 64 + j * 16 + l16, c);
#pragma unroll
        for (int i = 0; i < 4; ++i)
#pragma unroll
            for (int j = 0; j < 4; ++j)
                acc[i][j] = __builtin_amdgcn_mfma_f32_16x16x32_bf16(
                    b[j], a[i], acc[i][j], 0, 0, 0);   // swapped: D[chan][node]
    }
}

__global__ __launch_bounds__(256) void gemm1_mfma(
    const unsigned short* __restrict__ mean1b, const unsigned short* __restrict__ xb,
    const unsigned short* __restrict__ W1lb,   const unsigned short* __restrict__ W1rb,
    const float* __restrict__ b1l, unsigned short* __restrict__ hb)
{
    __shared__ unsigned short As[128 * 64];
    __shared__ unsigned short Bs[128 * 64];
    const int tid = threadIdx.x;
    const int wid = tid >> 6, lane = tid & 63;
    const int wm = wid & 1, wn = wid >> 1;
    const int l16 = lane & 15, quad = lane >> 4;
    const int rowBase = blockIdx.x * 128;
    const int colBase = blockIdx.y * 128;

    f32x4 z = {0.f, 0.f, 0.f, 0.f};
    f32x4 acc[4][4];
#pragma unroll
    for (int i = 0; i < 4; ++i)
#pragma unroll
        for (int j = 0; j < 4; ++j) acc[i][j] = z;

#pragma unroll
    for (int op = 0; op < 2; ++op) {
        const unsigned short* A = op ? xb : mean1b;
        const unsigned short* B = op ? W1rb : W1lb;
#pragma unroll
        for (int kb = 0; kb < IN_CH; kb += 64) {
            __syncthreads();
            stage_async(A, IN_CH, rowBase, N_NODES, kb, As, tid);
            stage_async(B, IN_CH, colBase, HID_CH, kb, Bs, tid);
            __syncthreads();   // drains vmcnt(0): DMA complete before reads
            mfma_tile(As, Bs, wm, wn, l16, quad, acc);
        }
    }

#pragma unroll
    for (int i = 0; i < 4; ++i) {
        int m = rowBase + wm * 64 + i * 16 + l16;
        if (m >= N_NODES) continue;
#pragma unroll
        for (int j = 0; j < 4; ++j) {
            int col = colBase + wn * 64 + j * 16 + quad * 4;
            float4 bv = *reinterpret_cast<const float4*>(b1l + col);
            alignas(8) unsigned short t[4];
            t[0] = f32_bf16_rne(fmaxf(acc[i][j][0] + bv.x, 0.0f));
            t[1] = f32_bf16_rne(fmaxf(acc[i][j][1] + bv.y, 0.0f));
            t[2] = f32_bf16_rne(fmaxf(acc[i][j][2] + bv.z, 0.0f));
            t[3] = f32_bf16_rne(fmaxf(acc[i][j][3] + bv.w, 0.0f));
            *reinterpret_cast<uint2*>(hb + (size_t)m * HID_CH + col) =
                *reinterpret_cast<const uint2*>(t);
        }
    }
}

// GEMM2: blockIdx.y==0 -> p = h @ W2l^T (bf16); y==1 -> out = h @ W2r^T + b2l (f32)
__global__ __launch_bounds__(256) void gemm2_mfma(
    const unsigned short* __restrict__ hb, const unsigned short* __restrict__ W2lb,
    const unsigned short* __restrict__ W2rb, const float* __restrict__ b2l,
    unsigned short* __restrict__ pb, float* __restrict__ out)
{
    __shared__ unsigned short As[128 * 64];
    __shared__ unsigned short Bs[128 * 64];
    const int tid = threadIdx.x;
    const int wid = tid >> 6, lane = tid & 63;
    const int wm = wid & 1, wn = wid >> 1;
    const int l16 = lane & 15, quad = lane >> 4;
    const int rowBase = blockIdx.x * 128;
    const unsigned short* B = blockIdx.y ? W2rb : W2lb;

    f32x4 z = {0.f, 0.f, 0.f, 0.f};
    f32x4 acc[4][4];
#pragma unroll
    for (int i = 0; i < 4; ++i)
#pragma unroll
        for (int j = 0; j < 4; ++j) acc[i][j] = z;

#pragma unroll
    for (int kb = 0; kb < HID_CH; kb += 64) {
        __syncthreads();
        stage_async(hb, HID_CH, rowBase, N_NODES, kb, As, tid);
        stage_async(B, HID_CH, 0, OUT_CH, kb, Bs, tid);
        __syncthreads();
        mfma_tile(As, Bs, wm, wn, l16, quad, acc);
    }

    if (blockIdx.y == 0) {
#pragma unroll
        for (int i = 0; i < 4; ++i) {
            int m = rowBase + wm * 64 + i * 16 + l16;
            if (m >= N_NODES) continue;
#pragma unroll
            for (int j = 0; j < 4; ++j) {
                int col = wn * 64 + j * 16 + quad * 4;
                alignas(8) unsigned short t[4];
                t[0] = f32_bf16_rne(acc[i][j][0]);
                t[1] = f32_bf16_rne(acc[i][j][1]);
                t[2] = f32_bf16_rne(acc[i][j][2]);
                t[3] = f32_bf16_rne(acc[i][j][3]);
                *reinterpret_cast<uint2*>(pb + (size_t)m * OUT_CH + col) =
                    *reinterpret_cast<const uint2*>(t);
            }
        }
    } else {
#pragma unroll
        for (int i = 0; i < 4; ++i) {
            int m = rowBase + wm * 64 + i * 16 + l16;
            if (m >= N_NODES) continue;
#pragma unroll
            for (int j = 0; j < 4; ++j) {
                int col = wn * 64 + j * 16 + quad * 4;
                float4 bv = *reinterpret_cast<const float4*>(b2l + col);
                float4 o;
                o.x = acc[i][j][0] + bv.x;
                o.y = acc[i][j][1] + bv.y;
                o.z = acc[i][j][2] + bv.z;
                o.w = acc[i][j][3] + bv.w;
                *reinterpret_cast<float4*>(out + (size_t)m * OUT_CH + col) = o;
            }
        }
    }
}

extern "C" void kernel_launch(void* const* d_in, const int* in_sizes, int n_in,
                              void* d_out, int out_size, void* d_ws, size_t ws_size,
                              hipStream_t stream)
{
    const float* x   = (const float*)d_in[0];
    const int*   ei  = (const int*)d_in[1];
    const float* W1l = (const float*)d_in[2];
    const float* b1l = (const float*)d_in[3];
    const float* W1r = (const float*)d_in[4];
    const float* W2l = (const float*)d_in[5];
    const float* b2l = (const float*)d_in[6];
    const float* W2r = (const float*)d_in[7];

    const int E = in_sizes[1] / 2;
    const int* src = ei;
    const int* dst = ei + E;

    char* ws = (char*)d_ws;
    size_t off = 0;
    auto alloc = [&](size_t bytes) {
        void* p = ws + off;
        off += (bytes + 255) & ~(size_t)255;
        return p;
    };
    unsigned short* xb     = (unsigned short*)alloc((size_t)N_NODES * IN_CH * 2);
    unsigned short* mean1b = (unsigned short*)alloc((size_t)N_NODES * IN_CH * 2);
    unsigned short* hb     = (unsigned short*)alloc((size_t)N_NODES * HID_CH * 2);
    unsigned short* pb     = (unsigned short*)alloc((size_t)N_NODES * OUT_CH * 2);
    unsigned short* W1lb   = (unsigned short*)alloc((size_t)HID_CH * IN_CH * 2);
    unsigned short* W1rb   = (unsigned short*)alloc((size_t)HID_CH * IN_CH * 2);
    unsigned short* W2lb   = (unsigned short*)alloc((size_t)OUT_CH * HID_CH * 2);
    unsigned short* W2rb   = (unsigned short*)alloc((size_t)OUT_CH * HID_CH * 2);
    int* counts = (int*)alloc((size_t)NBNW * 4);
    int* S      = (int*)alloc((size_t)(NBNW + 1) * 4);
    int* pairs  = (int*)alloc((size_t)E * 4);
    int* rowptr = (int*)alloc((size_t)(N_NODES + 1) * 4);
    int* colidx = (int*)alloc((size_t)E * 4);
    float* out = (float*)d_out;

    const int chunk = (E + NWG - 1) / NWG;

    prep_kernel<<<NWG + XBLK + WBLK, 256, 0, stream>>>(
        src, dst, counts, E, chunk, x, xb,
        W1l, W1r, W2l, W2r, W1lb, W1rb, W2lb, W2rb);
    scan_all_kernel<<<1, 256, 0, stream>>>(counts, S);
    bscatter_kernel<<<NWG, 256, 0, stream>>>(src, dst, S, pairs, E, chunk);
    bsort_kernel<<<NB, 256, 0, stream>>>(pairs, S, rowptr, colidx);

    const int aggBlocks = (N_NODES + 3) / 4;     // 12500 per slice
    const int mBlocks = (N_NODES + 127) / 128;   // 391

    agg1_kernel<<<dim3(aggBlocks, 4), 256, 0, stream>>>(xb, rowptr, colidx, mean1b);
    gemm1_mfma<<<dim3(mBlocks, HID_CH / 128), 256, 0, stream>>>(
        mean1b, xb, W1lb, W1rb, b1l, hb);
    gemm2_mfma<<<dim3(mBlocks, 2), 256, 0, stream>>>(hb, W2lb, W2rb, b2l, pb, out);
    agg2_kernel<<<dim3(aggBlocks, 4), 256, 0, stream>>>(pb, rowptr, colidx, out);
}

// Round 11
// 234.432 us; speedup vs baseline: 1.3379x; 1.3379x over previous
//
#include <hip/hip_runtime.h>

#define N_NODES 50000
#define IN_CH   128
#define HID_CH  256
#define OUT_CH  128

#define NB    196          // buckets: dst>>8
#define NWG   64           // phase-1 workgroups
#define NBNW  (NB * NWG)   // 12544 = 256 * 49
#define SCHUNK 49          // scan elements per thread (12544/256)

#define XBLK  3125         // cvt-x blocks: 50000*128/8/256
#define WBLK  64           // cvt-weights blocks: 4*4096/256

typedef __attribute__((ext_vector_type(8))) short bf16x8;
typedef __attribute__((ext_vector_type(4))) float f32x4;
typedef __attribute__((ext_vector_type(2))) float f32x2;

__device__ __forceinline__ unsigned short f32_bf16_rne(float f) {
    unsigned u = __float_as_uint(f);
    unsigned r = u + 0x7fff + ((u >> 16) & 1);
    return (unsigned short)(r >> 16);
}

__device__ __forceinline__ void cvt8(const float* __restrict__ in,
                                     unsigned short* __restrict__ outp, size_t j)
{
    const float4* p = reinterpret_cast<const float4*>(in) + 2 * j;
    float4 a = p[0], b = p[1];
    alignas(16) unsigned short t[8] = {
        f32_bf16_rne(a.x), f32_bf16_rne(a.y), f32_bf16_rne(a.z), f32_bf16_rne(a.w),
        f32_bf16_rne(b.x), f32_bf16_rne(b.y), f32_bf16_rne(b.z), f32_bf16_rne(b.w)};
    *reinterpret_cast<int4*>(outp + 8 * j) = *reinterpret_cast<const int4*>(t);
}

// ---------------------------------------------------------------------------
// prep: role-dispatched fusion of {bucket-count, cvt x (bf16 + fp8), cvt W}
// ---------------------------------------------------------------------------
__global__ __launch_bounds__(256) void prep_kernel(
    const int* __restrict__ src, const int* __restrict__ dst,
    int* __restrict__ counts, int E, int chunk,
    const float* __restrict__ x, unsigned short* __restrict__ xb,
    unsigned char* __restrict__ xb8,
    const float* __restrict__ W1l, const float* __restrict__ W1r,
    const float* __restrict__ W2l, const float* __restrict__ W2r,
    unsigned short* __restrict__ W1lb, unsigned short* __restrict__ W1rb,
    unsigned short* __restrict__ W2lb, unsigned short* __restrict__ W2rb)
{
    const int b = blockIdx.x;
    if (b < NWG) {
        __shared__ int h[NB];
        for (int i = threadIdx.x; i < NB; i += 256) h[i] = 0;
        __syncthreads();
        const int e0 = b * chunk;
        const int e1 = min(e0 + chunk, E);
        for (int e = e0 + threadIdx.x; e < e1; e += 256) {
            int s = src[e], d = dst[e];
            if ((unsigned)s < (unsigned)N_NODES && (unsigned)d < (unsigned)N_NODES)
                atomicAdd(&h[d >> 8], 1);
        }
        __syncthreads();
        for (int i = threadIdx.x; i < NB; i += 256)
            counts[i * NWG + b] = h[i];
    } else if (b < NWG + XBLK) {
        size_t j = (size_t)(b - NWG) * 256 + threadIdx.x;   // < 800000 exactly
        const float4* p = reinterpret_cast<const float4*>(x) + 2 * j;
        float4 a = p[0], bb = p[1];
        alignas(16) unsigned short t[8] = {
            f32_bf16_rne(a.x),  f32_bf16_rne(a.y),  f32_bf16_rne(a.z),  f32_bf16_rne(a.w),
            f32_bf16_rne(bb.x), f32_bf16_rne(bb.y), f32_bf16_rne(bb.z), f32_bf16_rne(bb.w)};
        *reinterpret_cast<int4*>(xb + 8 * j) = *reinterpret_cast<const int4*>(t);
        unsigned u0 = __builtin_amdgcn_cvt_pk_fp8_f32(a.x, a.y, 0, false);
        u0 = __builtin_amdgcn_cvt_pk_fp8_f32(a.z, a.w, u0, true);
        unsigned u1 = __builtin_amdgcn_cvt_pk_fp8_f32(bb.x, bb.y, 0, false);
        u1 = __builtin_amdgcn_cvt_pk_fp8_f32(bb.z, bb.w, u1, true);
        uint2 uv; uv.x = u0; uv.y = u1;
        *reinterpret_cast<uint2*>(xb8 + 8 * j) = uv;
    } else {
        int idx = (b - NWG - XBLK) * 256 + threadIdx.x;     // 0..16383
        int seg = idx >> 12, j = idx & 4095;
        const float* in = (seg == 0) ? W1l : (seg == 1) ? W1r : (seg == 2) ? W2l : W2r;
        unsigned short* o = (seg == 0) ? W1lb : (seg == 1) ? W1rb : (seg == 2) ? W2lb : W2rb;
        cvt8(in, o, (size_t)j);
    }
}

// ---------------------------------------------------------------------------
// Single-block exclusive scan of counts[NBNW] -> S, S[NBNW] = total
// ---------------------------------------------------------------------------
__global__ __launch_bounds__(256) void scan_all_kernel(
    const int* __restrict__ counts, int* __restrict__ S)
{
    __shared__ int tot[256];
    const int t = threadIdx.x;
    const int base = t * SCHUNK;
    int loc[SCHUNK];
    int sum = 0;
#pragma unroll
    for (int k = 0; k < SCHUNK; ++k) {
        loc[k] = sum;
        sum += counts[base + k];
    }
    tot[t] = sum;
    __syncthreads();
    for (int off = 1; off < 256; off <<= 1) {
        int v = (t >= off) ? tot[t - off] : 0;
        __syncthreads();
        if (t >= off) tot[t] += v;
        __syncthreads();
    }
    int offv = (t == 0) ? 0 : tot[t - 1];
#pragma unroll
    for (int k = 0; k < SCHUNK; ++k)
        S[base + k] = loc[k] + offv;
    if (t == 255) S[NBNW] = offv + sum;
}

// ---------------------------------------------------------------------------
// Scatter packed (src<<8 | dst&255) into (bucket,wg)-exclusive subregions.
// ---------------------------------------------------------------------------
__global__ __launch_bounds__(256) void bscatter_kernel(
    const int* __restrict__ src, const int* __restrict__ dst,
    const int* __restrict__ S, int* __restrict__ pairs, int E, int chunk)
{
    __shared__ int cur[NB];
    const int w = blockIdx.x;
    for (int i = threadIdx.x; i < NB; i += 256) cur[i] = S[i * NWG + w];
    __syncthreads();
    const int e0 = w * chunk;
    const int e1 = min(e0 + chunk, E);
    for (int e = e0 + threadIdx.x; e < e1; e += 256) {
        int s = src[e], d = dst[e];
        if ((unsigned)s < (unsigned)N_NODES && (unsigned)d < (unsigned)N_NODES) {
            int pos = atomicAdd(&cur[d >> 8], 1);
            pairs[pos] = (s << 8) | (d & 255);
        }
    }
}

// ---------------------------------------------------------------------------
// Per-bucket local counting sort -> rowptr + colidx
// ---------------------------------------------------------------------------
__global__ __launch_bounds__(256) void bsort_kernel(
    const int* __restrict__ pairs, const int* __restrict__ S,
    int* __restrict__ rowptr, int* __restrict__ colidx)
{
    __shared__ int hcnt[256];
    __shared__ int hcur[256];
    const int b = blockIdx.x;
    const int start = S[b * NWG];
    const int endv  = (b == NB - 1) ? S[NBNW] : S[(b + 1) * NWG];

    hcnt[threadIdx.x] = 0;
    __syncthreads();
    for (int e = start + threadIdx.x; e < endv; e += 256)
        atomicAdd(&hcnt[pairs[e] & 255], 1);
    __syncthreads();
    for (int off = 1; off < 256; off <<= 1) {
        int t = (threadIdx.x >= off) ? hcnt[threadIdx.x - off] : 0;
        __syncthreads();
        if (threadIdx.x >= off) hcnt[threadIdx.x] += t;
        __syncthreads();
    }
    int offv = (threadIdx.x == 0) ? 0 : hcnt[threadIdx.x - 1];
    hcur[threadIdx.x] = offv;
    int node = (b << 8) + threadIdx.x;
    if (node < N_NODES) rowptr[node] = start + offv;
    if (b == NB - 1 && threadIdx.x == 0) rowptr[N_NODES] = endv;
    __syncthreads();
    for (int e = start + threadIdx.x; e < endv; e += 256) {
        int p = pairs[e];
        int pos = atomicAdd(&hcur[p & 255], 1);
        colidx[start + pos] = (unsigned)p >> 8;
    }
}

// ---------------------------------------------------------------------------
// fp8-payload aggregates, r8 structure (proven): one wave per node, 4 groups
// of 16 lanes take contiguous quarters, 4-deep MLP. Row = 128 B (fp8), lane
// loads uint2 (8 ch), fp32 accumulate via HW v_cvt_pk_f32_fp8.
// r9/r10 lesson: channel slicing can't bound the working set (slice must
// follow the SOURCE row, but every destination needs all channels) — the
// only byte-level lever on the L3 gather floor is a narrower payload.
// ---------------------------------------------------------------------------
#define ACC8(v)                                                              \
    { f32x2 t0 = __builtin_amdgcn_cvt_pk_f32_fp8(v.x, false);                \
      f32x2 t1 = __builtin_amdgcn_cvt_pk_f32_fp8(v.x, true);                 \
      f32x2 t2 = __builtin_amdgcn_cvt_pk_f32_fp8(v.y, false);                \
      f32x2 t3 = __builtin_amdgcn_cvt_pk_f32_fp8(v.y, true);                 \
      acc[0] += t0.x; acc[1] += t0.y; acc[2] += t1.x; acc[3] += t1.y;        \
      acc[4] += t2.x; acc[5] += t2.y; acc[6] += t3.x; acc[7] += t3.y; }

#define AGG_BODY(CH)                                                            \
    const int node = blockIdx.x * 4 + (threadIdx.x >> 6);                       \
    if (node >= N_NODES) return;                                                \
    const int lane = threadIdx.x & 63;                                          \
    const int grp = lane >> 4, ch = lane & 15;                                  \
    const int beg = rowptr[node], end = rowptr[node + 1];                       \
    const int len = end - beg;                                                  \
    const int q = (len + 3) >> 2;                                               \
    int j  = beg + grp * q;                                                     \
    int j1 = min(j + q, end);                                                   \
    float acc[8] = {};                                                          \
    for (; j + 3 < j1; j += 4) {                                                \
        int s0 = colidx[j],     s1 = colidx[j + 1];                             \
        int s2 = colidx[j + 2], s3 = colidx[j + 3];                             \
        uint2 v0 = *reinterpret_cast<const uint2*>(feat + (size_t)s0 * CH + ch * 8); \
        uint2 v1 = *reinterpret_cast<const uint2*>(feat + (size_t)s1 * CH + ch * 8); \
        uint2 v2 = *reinterpret_cast<const uint2*>(feat + (size_t)s2 * CH + ch * 8); \
        uint2 v3 = *reinterpret_cast<const uint2*>(feat + (size_t)s3 * CH + ch * 8); \
        ACC8(v0) ACC8(v1) ACC8(v2) ACC8(v3)                                     \
    }                                                                           \
    for (; j < j1; ++j) {                                                       \
        int s0 = colidx[j];                                                     \
        uint2 v0 = *reinterpret_cast<const uint2*>(feat + (size_t)s0 * CH + ch * 8); \
        ACC8(v0)                                                                \
    }                                                                           \
    _Pragma("unroll")                                                           \
    for (int k = 0; k < 8; ++k) {                                               \
        acc[k] += __shfl_xor(acc[k], 16);                                       \
        acc[k] += __shfl_xor(acc[k], 32);                                       \
    }                                                                           \
    const float sc = 1.0f / fmaxf((float)len, 1.0f);

__global__ __launch_bounds__(256) void agg1_kernel(
    const unsigned char* __restrict__ feat, const int* __restrict__ rowptr,
    const int* __restrict__ colidx, unsigned short* __restrict__ outp)
{
    AGG_BODY(IN_CH)
    if (grp == 0) {
        alignas(16) unsigned short t[8];
#pragma unroll
        for (int k = 0; k < 8; ++k) t[k] = f32_bf16_rne(acc[k] * sc);
        *reinterpret_cast<int4*>(outp + (size_t)node * IN_CH + ch * 8) =
            *reinterpret_cast<const int4*>(t);
    }
}

__global__ __launch_bounds__(256) void agg2_kernel(
    const unsigned char* __restrict__ feat, const int* __restrict__ rowptr,
    const int* __restrict__ colidx, float* __restrict__ out)
{
    AGG_BODY(OUT_CH)
    if (grp == 0) {
        float* o = out + (size_t)node * OUT_CH + ch * 8;
        float4 o0 = reinterpret_cast<float4*>(o)[0];
        float4 o1 = reinterpret_cast<float4*>(o)[1];
        o0.x += acc[0] * sc; o0.y += acc[1] * sc; o0.z += acc[2] * sc; o0.w += acc[3] * sc;
        o1.x += acc[4] * sc; o1.y += acc[5] * sc; o1.z += acc[6] * sc; o1.w += acc[7] * sc;
        reinterpret_cast<float4*>(o)[0] = o0;
        reinterpret_cast<float4*>(o)[1] = o1;
    }
}

// ---------------------------------------------------------------------------
// MFMA GEMMs — 128x128 block tile, 4 waves (2x2), wave tile 64x64,
// mfma(b, a, acc) swapped epilogue (D[chan][node], vector stores).
// global->LDS via __builtin_amdgcn_global_load_lds width=16 + XOR chunk swizzle.
// ---------------------------------------------------------------------------
__device__ __forceinline__ void stage_async(
    const unsigned short* __restrict__ g, int ldg, int rowBase, int maxRow,
    int kBase, unsigned short* __restrict__ s, int tid)
{
    const int wave = tid >> 6;          // wave-uniform
    const int lane = tid & 63;
    const int r_in = lane >> 3;         // 0..7 within 8-row group
    const int c_g  = (lane & 7) ^ r_in; // fetch the chunk destined for this lane's LDS slot
#pragma unroll
    for (int it = 0; it < 4; ++it) {
        const int rowBlk = it * 32 + wave * 8;        // wave-uniform
        int row = rowBase + rowBlk + r_in;
        if (row >= maxRow) row = maxRow - 1;          // clamp; epilogue guards stores
        const unsigned short* gp = g + (size_t)row * ldg + kBase + c_g * 8;
        unsigned short* lp = s + rowBlk * 64;         // wave-uniform; HW adds lane*16
        __builtin_amdgcn_global_load_lds(
            (const __attribute__((address_space(1))) unsigned int*)gp,
            (__attribute__((address_space(3))) unsigned int*)lp,
            16, 0, 0);
    }
}

__device__ __forceinline__ const bf16x8* frag_ptr(
    const unsigned short* __restrict__ s, int rr, int c)
{
    return reinterpret_cast<const bf16x8*>(s + rr * 64 + (((c ^ (rr & 7))) << 3));
}

__device__ __forceinline__ void mfma_tile(
    const unsigned short* __restrict__ As, const unsigned short* __restrict__ Bs,
    int wm, int wn, int l16, int quad, f32x4 acc[4][4])
{
#pragma unroll
    for (int k0 = 0; k0 < 64; k0 += 32) {
        const int c = (k0 >> 3) + quad;   // 16 B chunk index within row
        bf16x8 a[4], b[4];
#pragma unroll
        for (int i = 0; i < 4; ++i)
            a[i] = *frag_ptr(As, wm * 64 + i * 16 + l16, c);
#pragma unroll
        for (int j = 0; j < 4; ++j)
            b[j] = *frag_ptr(Bs, wn * 64 + j * 16 + l16, c);
#pragma unroll
        for (int i = 0; i < 4; ++i)
#pragma unroll
            for (int j = 0; j < 4; ++j)
                acc[i][j] = __builtin_amdgcn_mfma_f32_16x16x32_bf16(
                    b[j], a[i], acc[i][j], 0, 0, 0);   // swapped: D[chan][node]
    }
}

__global__ __launch_bounds__(256) void gemm1_mfma(
    const unsigned short* __restrict__ mean1b, const unsigned short* __restrict__ xb,
    const unsigned short* __restrict__ W1lb,   const unsigned short* __restrict__ W1rb,
    const float* __restrict__ b1l, unsigned short* __restrict__ hb)
{
    __shared__ unsigned short As[128 * 64];
    __shared__ unsigned short Bs[128 * 64];
    const int tid = threadIdx.x;
    const int wid = tid >> 6, lane = tid & 63;
    const int wm = wid & 1, wn = wid >> 1;
    const int l16 = lane & 15, quad = lane >> 4;
    const int rowBase = blockIdx.x * 128;
    const int colBase = blockIdx.y * 128;

    f32x4 z = {0.f, 0.f, 0.f, 0.f};
    f32x4 acc[4][4];
#pragma unroll
    for (int i = 0; i < 4; ++i)
#pragma unroll
        for (int j = 0; j < 4; ++j) acc[i][j] = z;

#pragma unroll
    for (int op = 0; op < 2; ++op) {
        const unsigned short* A = op ? xb : mean1b;
        const unsigned short* B = op ? W1rb : W1lb;
#pragma unroll
        for (int kb = 0; kb < IN_CH; kb += 64) {
            __syncthreads();
            stage_async(A, IN_CH, rowBase, N_NODES, kb, As, tid);
            stage_async(B, IN_CH, colBase, HID_CH, kb, Bs, tid);
            __syncthreads();   // drains vmcnt(0): DMA complete before reads
            mfma_tile(As, Bs, wm, wn, l16, quad, acc);
        }
    }

#pragma unroll
    for (int i = 0; i < 4; ++i) {
        int m = rowBase + wm * 64 + i * 16 + l16;
        if (m >= N_NODES) continue;
#pragma unroll
        for (int j = 0; j < 4; ++j) {
            int col = colBase + wn * 64 + j * 16 + quad * 4;
            float4 bv = *reinterpret_cast<const float4*>(b1l + col);
            alignas(8) unsigned short t[4];
            t[0] = f32_bf16_rne(fmaxf(acc[i][j][0] + bv.x, 0.0f));
            t[1] = f32_bf16_rne(fmaxf(acc[i][j][1] + bv.y, 0.0f));
            t[2] = f32_bf16_rne(fmaxf(acc[i][j][2] + bv.z, 0.0f));
            t[3] = f32_bf16_rne(fmaxf(acc[i][j][3] + bv.w, 0.0f));
            *reinterpret_cast<uint2*>(hb + (size_t)m * HID_CH + col) =
                *reinterpret_cast<const uint2*>(t);
        }
    }
}

// GEMM2: blockIdx.y==0 -> p = h @ W2l^T (fp8 payload for agg2's gather);
//        y==1 -> out = h @ W2r^T + b2l (f32)
__global__ __launch_bounds__(256) void gemm2_mfma(
    const unsigned short* __restrict__ hb, const unsigned short* __restrict__ W2lb,
    const unsigned short* __restrict__ W2rb, const float* __restrict__ b2l,
    unsigned char* __restrict__ pb8, float* __restrict__ out)
{
    __shared__ unsigned short As[128 * 64];
    __shared__ unsigned short Bs[128 * 64];
    const int tid = threadIdx.x;
    const int wid = tid >> 6, lane = tid & 63;
    const int wm = wid & 1, wn = wid >> 1;
    const int l16 = lane & 15, quad = lane >> 4;
    const int rowBase = blockIdx.x * 128;
    const unsigned short* B = blockIdx.y ? W2rb : W2lb;

    f32x4 z = {0.f, 0.f, 0.f, 0.f};
    f32x4 acc[4][4];
#pragma unroll
    for (int i = 0; i < 4; ++i)
#pragma unroll
        for (int j = 0; j < 4; ++j) acc[i][j] = z;

#pragma unroll
    for (int kb = 0; kb < HID_CH; kb += 64) {
        __syncthreads();
        stage_async(hb, HID_CH, rowBase, N_NODES, kb, As, tid);
        stage_async(B, HID_CH, 0, OUT_CH, kb, Bs, tid);
        __syncthreads();
        mfma_tile(As, Bs, wm, wn, l16, quad, acc);
    }

    if (blockIdx.y == 0) {
#pragma unroll
        for (int i = 0; i < 4; ++i) {
            int m = rowBase + wm * 64 + i * 16 + l16;
            if (m >= N_NODES) continue;
#pragma unroll
            for (int j = 0; j < 4; ++j) {
                int col = wn * 64 + j * 16 + quad * 4;
                unsigned u = __builtin_amdgcn_cvt_pk_fp8_f32(
                    acc[i][j][0], acc[i][j][1], 0, false);
                u = __builtin_amdgcn_cvt_pk_fp8_f32(
                    acc[i][j][2], acc[i][j][3], u, true);
                *reinterpret_cast<unsigned*>(pb8 + (size_t)m * OUT_CH + col) = u;
            }
        }
    } else {
#pragma unroll
        for (int i = 0; i < 4; ++i) {
            int m = rowBase + wm * 64 + i * 16 + l16;
            if (m >= N_NODES) continue;
#pragma unroll
            for (int j = 0; j < 4; ++j) {
                int col = wn * 64 + j * 16 + quad * 4;
                float4 bv = *reinterpret_cast<const float4*>(b2l + col);
                float4 o;
                o.x = acc[i][j][0] + bv.x;
                o.y = acc[i][j][1] + bv.y;
                o.z = acc[i][j][2] + bv.z;
                o.w = acc[i][j][3] + bv.w;
                *reinterpret_cast<float4*>(out + (size_t)m * OUT_CH + col) = o;
            }
        }
    }
}

extern "C" void kernel_launch(void* const* d_in, const int* in_sizes, int n_in,
                              void* d_out, int out_size, void* d_ws, size_t ws_size,
                              hipStream_t stream)
{
    const float* x   = (const float*)d_in[0];
    const int*   ei  = (const int*)d_in[1];
    const float* W1l = (const float*)d_in[2];
    const float* b1l = (const float*)d_in[3];
    const float* W1r = (const float*)d_in[4];
    const float* W2l = (const float*)d_in[5];
    const float* b2l = (const float*)d_in[6];
    const float* W2r = (const float*)d_in[7];

    const int E = in_sizes[1] / 2;
    const int* src = ei;
    const int* dst = ei + E;

    char* ws = (char*)d_ws;
    size_t off = 0;
    auto alloc = [&](size_t bytes) {
        void* p = ws + off;
        off += (bytes + 255) & ~(size_t)255;
        return p;
    };
    unsigned short* xb     = (unsigned short*)alloc((size_t)N_NODES * IN_CH * 2);
    unsigned char*  xb8    = (unsigned char*)alloc((size_t)N_NODES * IN_CH);
    unsigned short* mean1b = (unsigned short*)alloc((size_t)N_NODES * IN_CH * 2);
    unsigned short* hb     = (unsigned short*)alloc((size_t)N_NODES * HID_CH * 2);
    unsigned char*  pb8    = (unsigned char*)alloc((size_t)N_NODES * OUT_CH);
    unsigned short* W1lb   = (unsigned short*)alloc((size_t)HID_CH * IN_CH * 2);
    unsigned short* W1rb   = (unsigned short*)alloc((size_t)HID_CH * IN_CH * 2);
    unsigned short* W2lb   = (unsigned short*)alloc((size_t)OUT_CH * HID_CH * 2);
    unsigned short* W2rb   = (unsigned short*)alloc((size_t)OUT_CH * HID_CH * 2);
    int* counts = (int*)alloc((size_t)NBNW * 4);
    int* S      = (int*)alloc((size_t)(NBNW + 1) * 4);
    int* pairs  = (int*)alloc((size_t)E * 4);
    int* rowptr = (int*)alloc((size_t)(N_NODES + 1) * 4);
    int* colidx = (int*)alloc((size_t)E * 4);
    float* out = (float*)d_out;

    const int chunk = (E + NWG - 1) / NWG;

    prep_kernel<<<NWG + XBLK + WBLK, 256, 0, stream>>>(
        src, dst, counts, E, chunk, x, xb, xb8,
        W1l, W1r, W2l, W2r, W1lb, W1rb, W2lb, W2rb);
    scan_all_kernel<<<1, 256, 0, stream>>>(counts, S);
    bscatter_kernel<<<NWG, 256, 0, stream>>>(src, dst, S, pairs, E, chunk);
    bsort_kernel<<<NB, 256, 0, stream>>>(pairs, S, rowptr, colidx);

    const int aggBlocks = (N_NODES + 3) / 4;     // 12500
    const int mBlocks = (N_NODES + 127) / 128;   // 391

    agg1_kernel<<<aggBlocks, 256, 0, stream>>>(xb8, rowptr, colidx, mean1b);
    gemm1_mfma<<<dim3(mBlocks, HID_CH / 128), 256, 0, stream>>>(
        mean1b, xb, W1lb, W1rb, b1l, hb);
    gemm2_mfma<<<dim3(mBlocks, 2), 256, 0, stream>>>(hb, W2lb, W2rb, b2l, pb8, out);
    agg2_kernel<<<aggBlocks, 256, 0, stream>>>(pb8, rowptr, colidx, out);
}